// Round 5
// baseline (5570.226 us; speedup 1.0000x reference)
//
#include <hip/hip_runtime.h>
#include <math.h>

typedef _Float16 f16;
typedef _Float16 f16x8 __attribute__((ext_vector_type(8)));
typedef float f32x4 __attribute__((ext_vector_type(4)));

// Problem dims
#define T_ 1024
#define B_ 128
#define DI_ 256
#define DL_ 512
#define V_ 10000

// ws layout (bytes)
#define OFF_EMBH   0u          // V*DI fp16 = 5,120,000
#define OFF_WIT    5120000u    // [512][256] fp16 = 262,144 (WiT[n][k] = Wi[k][n])
#define OFF_WFRAG  5382144u    // 32 tiles x 16 kk x 64 lanes x 8 f16 = 524,288 (frag-linear Wh)
#define OFF_BSUM   5906432u    // 512 f32 = 2048 (bi + bh)

// fast tanh: 1 - 2/(exp(2x)+1) via v_exp_f32 + v_rcp_f32 (~1e-6 abs err)
__device__ __forceinline__ float fast_tanh(float x) {
  float xx = fminf(fmaxf(x, -10.f), 10.f);
  float e = __builtin_amdgcn_exp2f(xx * 2.88539008177793f);  // exp(2x)
  return 1.f - 2.f * __builtin_amdgcn_rcpf(e + 1.f);
}

// ---------------- prep kernels ----------------
__global__ void prep_emb_k(const float* __restrict__ emb, f16* __restrict__ embH, int n) {
  for (int i = blockIdx.x * blockDim.x + threadIdx.x; i < n; i += gridDim.x * blockDim.x)
    embH[i] = (f16)emb[i];
}

// WiT[n][k] = Wi[k][n]; Wfrag fragment-linear Wh; bsum = bi + bh
__global__ void prep_w_k(const float* __restrict__ Wi, const float* __restrict__ Wh,
                         const float* __restrict__ bi, const float* __restrict__ bh,
                         f16* __restrict__ WiT, f16* __restrict__ Wfrag,
                         float* __restrict__ bsum) {
  int i = blockIdx.x * blockDim.x + threadIdx.x;
  if (i < 131072) {                       // WiT
    int n = i & 511, k = i >> 9;
    WiT[n * 256 + k] = (f16)Wi[k * 512 + n];
  } else if (i < 131072 + 32768) {        // Wfrag[ct][kk][l][8]
    int s = i - 131072;
    int l = s & 63, kk = (s >> 6) & 15, ct = s >> 10;
    int n = ct * 16 + (l & 15);
    int kbase = kk * 32 + (l >> 4) * 8;
    f16 tmp[8];
#pragma unroll
    for (int e = 0; e < 8; e++) tmp[e] = (f16)Wh[(size_t)(kbase + e) * 512 + n];
    *(f16x8*)&Wfrag[(size_t)s * 8] = *(f16x8*)tmp;
  } else if (i < 131072 + 32768 + 512) {  // bsum
    int s = i - 131072 - 32768;
    bsum[s] = bi[s] + bh[s];
  }
}

// ---------------- phase A: PREfrag = gather(embH,X) @ Wi + bsum ----------------
// Output layout (overlaid on d_out): float offset t*65536 + c*8192 + ct*256 + lane*4 + r
// = acc fragment-linear per (t, batch-slice c, col-tile ct). Fully coalesced dwordx4.
__global__ __launch_bounds__(256) void gemmA_k(
    const int* __restrict__ X, const f16* __restrict__ embH,
    const f16* __restrict__ WiT, const float* __restrict__ bsum,
    float* __restrict__ out) {
  __shared__ f16 Ah[128][40];
  __shared__ f16 Bh[128][40];
  __shared__ int idxL[128];

  int tid = threadIdx.x;
  int lane = tid & 63, w = tid >> 6;
  int wr = w >> 1, wc = w & 1;
  int by = blockIdx.y, bx = blockIdx.x;
  int m0 = by * 128, n0 = bx * 128;

  if (tid < 128) {
    int v = X[m0 + tid];
    idxL[tid] = (v < 0) ? 0 : ((v >= V_) ? (V_ - 1) : v);
  }
  __syncthreads();

  f32x4 acc[4][4];
#pragma unroll
  for (int i = 0; i < 4; i++)
#pragma unroll
    for (int jj = 0; jj < 4; jj++) acc[i][jj] = (f32x4){0.f, 0.f, 0.f, 0.f};

  int ar = lane & 15, koff = (lane >> 4) * 8;

  for (int kk = 0; kk < 8; kk++) {
    int k0 = kk * 32;
#pragma unroll
    for (int q = 0; q < 2; q++) {
      int s = tid + 256 * q;
      int row = s >> 2, part = s & 3;
      *(uint4*)&Ah[row][part * 8] = *(const uint4*)&embH[idxL[row] * 256 + k0 + part * 8];
      *(uint4*)&Bh[row][part * 8] = *(const uint4*)&WiT[(n0 + row) * 256 + k0 + part * 8];
    }
    __syncthreads();
    f16x8 a[4], b[4];
#pragma unroll
    for (int i = 0; i < 4; i++) a[i] = *(const f16x8*)&Ah[wr * 64 + i * 16 + ar][koff];
#pragma unroll
    for (int jj = 0; jj < 4; jj++) b[jj] = *(const f16x8*)&Bh[wc * 64 + jj * 16 + ar][koff];
#pragma unroll
    for (int i = 0; i < 4; i++)
#pragma unroll
      for (int jj = 0; jj < 4; jj++)
        acc[i][jj] = __builtin_amdgcn_mfma_f32_16x16x32_f16(a[i], b[jj], acc[i][jj], 0, 0, 0);
    __syncthreads();
  }

  // PREfrag store: c = wr*4+i (batch-16-slice), ct = bx*8+wc*4+jj (col-tile)
#pragma unroll
  for (int i = 0; i < 4; i++) {
#pragma unroll
    for (int jj = 0; jj < 4; jj++) {
      int c = wr * 4 + i;
      int ct = bx * 8 + wc * 4 + jj;
      float bs = bsum[ct * 16 + ar];
      f32x4 v = acc[i][jj];
      v[0] += bs; v[1] += bs; v[2] += bs; v[3] += bs;
      *(f32x4*)&out[(size_t)by * 65536 + (size_t)c * 8192 + ct * 256 + lane * 4] = v;
    }
  }
}

// ---------------- phase B: persistent recurrence, ZERO inter-WG comms ----------------
// 8 WGs, one per 16-row batch slice. Each WG computes ALL 512 cols.
// Wh (512 KB fp16, frag-linear) split per wave (128 cols = 8 col-tiles):
//   tiles w*8+0..3 in VGPRs (256/lane), w*8+4..5 in LDS (128 KB), w*8+6..7
//   streamed from L2 every step (same addrs across WGs -> L2-hot).
// h kept in LDS fragment-linear (hA); PRE read from / H written to the same
// (t,c) 32KB block of d_out (intra-WG overlay, barrier-ordered).
__global__ __launch_bounds__(256, 1) void rnnB_k(
    const float* __restrict__ h0, const f16* __restrict__ Wfrag,
    float* __restrict__ H) {
  __shared__ f16 Wlds[8 * 16 * 64 * 8];  // 131072 B: slot s=(w*2+q) <-> tile w*8+4+q
  __shared__ f16 hA[16 * 64 * 8];        // 16384 B: frag-linear h ([kk][lane][8])

  int tid = threadIdx.x, lane = tid & 63, w = tid >> 6;
  int c = blockIdx.x;          // batch slice: rows c*16..c*16+15
  int w8 = w * 8;
  int ar = lane & 15, r0 = (lane >> 4) * 4;

  const f16x8* Wfr = (const f16x8*)Wfrag;  // index: (ct*16+kk)*64 + lane

  // --- one-time: fill LDS weight slots ---
  for (int idx = tid; idx < 8192; idx += 256) {
    int l = idx & 63, kk = (idx >> 6) & 15, s = idx >> 10;
    int ts = (s >> 1) * 8 + 4 + (s & 1);
    *(f16x8*)&Wlds[(size_t)idx * 8] = Wfr[(ts * 16 + kk) * 64 + l];
  }
  // --- one-time: hA <- h0 (frag-linear scatter) ---
  for (int idx = tid; idx < 8192; idx += 256) {
    int kk = idx >> 9, l = (idx >> 3) & 63, e = idx & 7;
    int row = l & 15, k = kk * 32 + (l >> 4) * 8 + e;
    hA[idx] = (f16)h0[(size_t)(c * 16 + row) * 512 + k];
  }

  // --- one-time: register-resident weight tiles (w8+0..3) ---
  f16x8 Wreg[64];  // [ti][kk] = Wreg[ti*16+kk], static-indexed via unroll
#pragma unroll
  for (int ti = 0; ti < 4; ti++)
#pragma unroll
    for (int kk = 0; kk < 16; kk++)
      Wreg[ti * 16 + kk] = Wfr[((w8 + ti) * 16 + kk) * 64 + lane];

  int s6base = (w8 + 6) * 16 * 64 + lane;
  int s7base = (w8 + 7) * 16 * 64 + lane;
  int sl0 = w * 2, sl1 = w * 2 + 1;

  // prologue: stream kk=0 + pre(t=0)
  f16x8 ws6[2], ws7[2];
  ws6[0] = Wfr[s6base];
  ws7[0] = Wfr[s7base];
  f32x4 pre[8];
  {
    const f32x4* preb = (const f32x4*)(H + (size_t)c * 8192);  // t=0 block
#pragma unroll
    for (int ti = 0; ti < 8; ti++) pre[ti] = preb[(w8 + ti) * 64 + lane];
  }

  for (int t = 0; t < 1024; t++) {
    __syncthreads();  // B1: hA(t-1 epilogue) writes -> visible; drains pre/stream/H-store vmem

    f32x4 acc[8];
#pragma unroll
    for (int ti = 0; ti < 8; ti++) acc[ti] = (f32x4){0.f, 0.f, 0.f, 0.f};

#pragma unroll
    for (int kk = 0; kk < 16; kk++) {
      f16x8 a = *(const f16x8*)&hA[(size_t)(kk * 64 + lane) * 8];
      if (kk < 15) {
        ws6[(kk + 1) & 1] = Wfr[s6base + (kk + 1) * 64];
        ws7[(kk + 1) & 1] = Wfr[s7base + (kk + 1) * 64];
      }
      acc[0] = __builtin_amdgcn_mfma_f32_16x16x32_f16(a, Wreg[0 * 16 + kk], acc[0], 0, 0, 0);
      acc[1] = __builtin_amdgcn_mfma_f32_16x16x32_f16(a, Wreg[1 * 16 + kk], acc[1], 0, 0, 0);
      acc[2] = __builtin_amdgcn_mfma_f32_16x16x32_f16(a, Wreg[2 * 16 + kk], acc[2], 0, 0, 0);
      acc[3] = __builtin_amdgcn_mfma_f32_16x16x32_f16(a, Wreg[3 * 16 + kk], acc[3], 0, 0, 0);
      f16x8 w4 = *(const f16x8*)&Wlds[(size_t)((sl0 * 16 + kk) * 64 + lane) * 8];
      f16x8 w5 = *(const f16x8*)&Wlds[(size_t)((sl1 * 16 + kk) * 64 + lane) * 8];
      acc[4] = __builtin_amdgcn_mfma_f32_16x16x32_f16(a, w4, acc[4], 0, 0, 0);
      acc[5] = __builtin_amdgcn_mfma_f32_16x16x32_f16(a, w5, acc[5], 0, 0, 0);
      acc[6] = __builtin_amdgcn_mfma_f32_16x16x32_f16(a, ws6[kk & 1], acc[6], 0, 0, 0);
      acc[7] = __builtin_amdgcn_mfma_f32_16x16x32_f16(a, ws7[kk & 1], acc[7], 0, 0, 0);
    }

    __syncthreads();  // B2: all hA(t-1) reads done -> safe to overwrite with h_t

    // epilogue: h_t = tanh(pre + acc); store H(t) natural layout; hA <- h_t;
    // then issue pre(t+1) + stream kk=0 for next step (drained/ordered by B1).
    float* Hblk = H + (size_t)t * 65536 + (size_t)c * 8192;
#pragma unroll
    for (int ti = 0; ti < 8; ti++) {
      int ct = w8 + ti;
      int kkA = ct >> 1;
#pragma unroll
      for (int r = 0; r < 4; r++) {
        float v = fast_tanh(acc[ti][r] + pre[ti][r]);
        Hblk[(size_t)(r0 + r) * 512 + ct * 16 + ar] = v;
        int lA = (r0 + r) | ((((ct & 1) << 1) | (ar >> 3)) << 4);
        hA[((kkA * 64 + lA) << 3) + (ar & 7)] = (f16)v;
      }
    }

    int tn = (t < 1023) ? t + 1 : 0;  // clamp: last iteration loads dummy (discarded)
    const f32x4* preb = (const f32x4*)(H + (size_t)tn * 65536 + (size_t)c * 8192);
#pragma unroll
    for (int ti = 0; ti < 8; ti++) pre[ti] = preb[(w8 + ti) * 64 + lane];
    ws6[0] = Wfr[s6base];
    ws7[0] = Wfr[s7base];
  }
}

// ---------------- launch ----------------
extern "C" void kernel_launch(void* const* d_in, const int* in_sizes, int n_in,
                              void* d_out, int out_size, void* d_ws, size_t ws_size,
                              hipStream_t stream) {
  const int* X     = (const int*)d_in[0];   // int32 (harness stores integer inputs as int32)
  const float* h0  = (const float*)d_in[1];
  const float* emb = (const float*)d_in[2];
  const float* Wi  = (const float*)d_in[3];
  const float* bi  = (const float*)d_in[4];
  const float* Wh  = (const float*)d_in[5];
  const float* bh  = (const float*)d_in[6];
  float* H = (float*)d_out;

  char* ws = (char*)d_ws;
  f16* embH   = (f16*)(ws + OFF_EMBH);
  f16* WiT    = (f16*)(ws + OFF_WIT);
  f16* Wfrag  = (f16*)(ws + OFF_WFRAG);
  float* bsum = (float*)(ws + OFF_BSUM);

  prep_emb_k<<<2560, 256, 0, stream>>>(emb, embH, V_ * DI_);
  prep_w_k<<<642, 256, 0, stream>>>(Wi, Wh, bi, bh, WiT, Wfrag, bsum);
  gemmA_k<<<dim3(4, 1024), 256, 0, stream>>>(X, embH, WiT, bsum, H);
  rnnB_k<<<8, 256, 0, stream>>>(h0, Wfrag, H);
}

// Round 6
// 3468.995 us; speedup vs baseline: 1.6057x; 1.6057x over previous
//
#include <hip/hip_runtime.h>
#include <math.h>

typedef _Float16 f16;
typedef _Float16 f16x8 __attribute__((ext_vector_type(8)));
typedef float f32x4 __attribute__((ext_vector_type(4)));

// Problem dims
#define T_ 1024
#define B_ 128
#define DI_ 256
#define DL_ 512
#define V_ 10000

// ws layout (bytes)
#define OFF_EMBH   0u          // V*DI fp16 = 5,120,000
#define OFF_WIT    5120000u    // [512][256] fp16 = 262,144 (WiT[n][k] = Wi[k][n])
#define OFF_WFRAG  5382144u    // 32 tiles x 16 kk x 64 lanes x 8 f16 = 524,288 (frag-linear Wh)
#define OFF_BSUM   5906432u    // 512 f32 = 2048 (bi + bh)

// fast tanh: 1 - 2/(exp(2x)+1). No clamp needed: exp2->inf gives 1, ->0 gives -1.
__device__ __forceinline__ float fast_tanh(float x) {
  float e = __builtin_amdgcn_exp2f(x * 2.88539008177793f);  // exp(2x)
  return 1.f - 2.f * __builtin_amdgcn_rcpf(e + 1.f);
}

// ---------------- prep kernels ----------------
__global__ void prep_emb_k(const float* __restrict__ emb, f16* __restrict__ embH, int n) {
  for (int i = blockIdx.x * blockDim.x + threadIdx.x; i < n; i += gridDim.x * blockDim.x)
    embH[i] = (f16)emb[i];
}

// WiT[n][k] = Wi[k][n]; Wfrag fragment-linear Wh; bsum = bi + bh
__global__ void prep_w_k(const float* __restrict__ Wi, const float* __restrict__ Wh,
                         const float* __restrict__ bi, const float* __restrict__ bh,
                         f16* __restrict__ WiT, f16* __restrict__ Wfrag,
                         float* __restrict__ bsum) {
  int i = blockIdx.x * blockDim.x + threadIdx.x;
  if (i < 131072) {                       // WiT
    int n = i & 511, k = i >> 9;
    WiT[n * 256 + k] = (f16)Wi[k * 512 + n];
  } else if (i < 131072 + 32768) {        // Wfrag[ct][kk][l][8]
    int s = i - 131072;
    int l = s & 63, kk = (s >> 6) & 15, ct = s >> 10;
    int n = ct * 16 + (l & 15);
    int kbase = kk * 32 + (l >> 4) * 8;
    f16 tmp[8];
#pragma unroll
    for (int e = 0; e < 8; e++) tmp[e] = (f16)Wh[(size_t)(kbase + e) * 512 + n];
    *(f16x8*)&Wfrag[(size_t)s * 8] = *(f16x8*)tmp;
  } else if (i < 131072 + 32768 + 512) {  // bsum
    int s = i - 131072 - 32768;
    bsum[s] = bi[s] + bh[s];
  }
}

// ---------------- phase A: PREfrag = gather(embH,X) @ Wi + bsum ----------------
// Output layout (overlaid on d_out): float offset t*65536 + c*8192 + ct*256 + lane*4 + r
__global__ __launch_bounds__(256) void gemmA_k(
    const int* __restrict__ X, const f16* __restrict__ embH,
    const f16* __restrict__ WiT, const float* __restrict__ bsum,
    float* __restrict__ out) {
  __shared__ f16 Ah[128][40];
  __shared__ f16 Bh[128][40];
  __shared__ int idxL[128];

  int tid = threadIdx.x;
  int lane = tid & 63, w = tid >> 6;
  int wr = w >> 1, wc = w & 1;
  int by = blockIdx.y, bx = blockIdx.x;
  int m0 = by * 128, n0 = bx * 128;

  if (tid < 128) {
    int v = X[m0 + tid];
    idxL[tid] = (v < 0) ? 0 : ((v >= V_) ? (V_ - 1) : v);
  }
  __syncthreads();

  f32x4 acc[4][4];
#pragma unroll
  for (int i = 0; i < 4; i++)
#pragma unroll
    for (int jj = 0; jj < 4; jj++) acc[i][jj] = (f32x4){0.f, 0.f, 0.f, 0.f};

  int ar = lane & 15, koff = (lane >> 4) * 8;

  for (int kk = 0; kk < 8; kk++) {
    int k0 = kk * 32;
#pragma unroll
    for (int q = 0; q < 2; q++) {
      int s = tid + 256 * q;
      int row = s >> 2, part = s & 3;
      *(uint4*)&Ah[row][part * 8] = *(const uint4*)&embH[idxL[row] * 256 + k0 + part * 8];
      *(uint4*)&Bh[row][part * 8] = *(const uint4*)&WiT[(n0 + row) * 256 + k0 + part * 8];
    }
    __syncthreads();
    f16x8 a[4], b[4];
#pragma unroll
    for (int i = 0; i < 4; i++) a[i] = *(const f16x8*)&Ah[wr * 64 + i * 16 + ar][koff];
#pragma unroll
    for (int jj = 0; jj < 4; jj++) b[jj] = *(const f16x8*)&Bh[wc * 64 + jj * 16 + ar][koff];
#pragma unroll
    for (int i = 0; i < 4; i++)
#pragma unroll
      for (int jj = 0; jj < 4; jj++)
        acc[i][jj] = __builtin_amdgcn_mfma_f32_16x16x32_f16(a[i], b[jj], acc[i][jj], 0, 0, 0);
    __syncthreads();
  }

#pragma unroll
  for (int i = 0; i < 4; i++) {
#pragma unroll
    for (int jj = 0; jj < 4; jj++) {
      int c = wr * 4 + i;
      int ct = bx * 8 + wc * 4 + jj;
      float bs = bsum[ct * 16 + ar];
      f32x4 v = acc[i][jj];
      v[0] += bs; v[1] += bs; v[2] += bs; v[3] += bs;
      *(f32x4*)&out[(size_t)by * 65536 + (size_t)c * 8192 + ct * 256 + lane * 4] = v;
    }
  }
}

// ---------------- phase B: persistent recurrence, ZERO inter-WG comms ----------------
// 8 WGs x 512 threads (8 waves -> 2 waves/SIMD). Wave w owns col-tiles 4w..4w+3:
// 3 tiles VGPR-resident (192 VGPR), 1 tile LDS-resident (8 tiles = 128 KB).
// Everything resident: no per-step global weight traffic at all.
// h kept in LDS fragment-linear (hA, 16 KB); PRE read from / H written to the
// same (t,c) 32 KB block of d_out (intra-WG overlay, barrier-ordered).
__global__ __launch_bounds__(512, 2) void rnnB_k(
    const float* __restrict__ h0, const f16* __restrict__ Wfrag,
    float* __restrict__ H) {
  __shared__ f16 Wlds[8 * 16 * 64 * 8];  // 131072 B: slot w <-> tile 4w+3
  __shared__ f16 hA[16 * 64 * 8];        // 16384 B: frag-linear h ([kk][lane][8])

  int tid = threadIdx.x, lane = tid & 63, w = tid >> 6;
  int c = blockIdx.x;          // batch slice: rows c*16..c*16+15
  int w4 = w * 4;
  int ar = lane & 15, r0 = (lane >> 4) * 4;

  const f16x8* Wfr = (const f16x8*)Wfrag;  // index: (ct*16+kk)*64 + lane

  // one-time: LDS weight slots (slot s <- tile 4s+3)
  for (int idx = tid; idx < 8192; idx += 512) {
    int l = idx & 63, kk = (idx >> 6) & 15, s = idx >> 10;
    *(f16x8*)&Wlds[(size_t)idx * 8] = Wfr[((s * 4 + 3) * 16 + kk) * 64 + l];
  }
  // one-time: hA <- h0 (frag-linear scatter)
  for (int idx = tid; idx < 8192; idx += 512) {
    int kk = idx >> 9, l = (idx >> 3) & 63, e = idx & 7;
    int row = l & 15, k = kk * 32 + (l >> 4) * 8 + e;
    hA[idx] = (f16)h0[(size_t)(c * 16 + row) * 512 + k];
  }

  // one-time: register-resident weight tiles 4w..4w+2 (192 VGPR, static-indexed)
  f16x8 Wreg[48];
#pragma unroll
  for (int ti = 0; ti < 3; ti++)
#pragma unroll
    for (int kk = 0; kk < 16; kk++)
      Wreg[ti * 16 + kk] = Wfr[((w4 + ti) * 16 + kk) * 64 + lane];

  // prologue: pre(t=0)
  f32x4 pre[4];
  {
    const f32x4* preb = (const f32x4*)(H + (size_t)c * 8192);
#pragma unroll
    for (int ti = 0; ti < 4; ti++) pre[ti] = preb[(w4 + ti) * 64 + lane];
  }

  for (int t = 0; t < 1024; t++) {
    __syncthreads();  // B1: hA writes (epilogue t-1 / init) visible; pre loads drained

    f32x4 acc[4];
#pragma unroll
    for (int ti = 0; ti < 4; ti++) acc[ti] = (f32x4){0.f, 0.f, 0.f, 0.f};

#pragma unroll
    for (int kk = 0; kk < 16; kk++) {
      f16x8 a = *(const f16x8*)&hA[(size_t)(kk * 64 + lane) * 8];
      f16x8 w3 = *(const f16x8*)&Wlds[(size_t)((w * 16 + kk) * 64 + lane) * 8];
      acc[0] = __builtin_amdgcn_mfma_f32_16x16x32_f16(a, Wreg[0 * 16 + kk], acc[0], 0, 0, 0);
      acc[1] = __builtin_amdgcn_mfma_f32_16x16x32_f16(a, Wreg[1 * 16 + kk], acc[1], 0, 0, 0);
      acc[2] = __builtin_amdgcn_mfma_f32_16x16x32_f16(a, Wreg[2 * 16 + kk], acc[2], 0, 0, 0);
      acc[3] = __builtin_amdgcn_mfma_f32_16x16x32_f16(a, w3, acc[3], 0, 0, 0);
    }

    __syncthreads();  // B2: all hA(t-1) reads done -> safe to overwrite

    // epilogue: h_t = tanh(pre + acc); store H(t) natural; hA <- h_t; prefetch pre(t+1)
    float* Hblk = H + (size_t)t * 65536 + (size_t)c * 8192;
#pragma unroll
    for (int ti = 0; ti < 4; ti++) {
      int ct = w4 + ti;
      int kkA = ct >> 1;
#pragma unroll
      for (int r = 0; r < 4; r++) {
        float v = fast_tanh(acc[ti][r] + pre[ti][r]);
        Hblk[(size_t)(r0 + r) * 512 + ct * 16 + ar] = v;
        int lA = (r0 + r) | ((((ct & 1) << 1) | (ar >> 3)) << 4);
        hA[((kkA * 64 + lA) << 3) + (ar & 7)] = (f16)v;
      }
    }

    int tn = (t < 1023) ? t + 1 : 0;  // last iter loads dummy (discarded)
    const f32x4* preb = (const f32x4*)(H + (size_t)tn * 65536 + (size_t)c * 8192);
#pragma unroll
    for (int ti = 0; ti < 4; ti++) pre[ti] = preb[(w4 + ti) * 64 + lane];
  }
}

// ---------------- launch ----------------
extern "C" void kernel_launch(void* const* d_in, const int* in_sizes, int n_in,
                              void* d_out, int out_size, void* d_ws, size_t ws_size,
                              hipStream_t stream) {
  const int* X     = (const int*)d_in[0];   // int32 (harness stores integer inputs as int32)
  const float* h0  = (const float*)d_in[1];
  const float* emb = (const float*)d_in[2];
  const float* Wi  = (const float*)d_in[3];
  const float* bi  = (const float*)d_in[4];
  const float* Wh  = (const float*)d_in[5];
  const float* bh  = (const float*)d_in[6];
  float* H = (float*)d_out;

  char* ws = (char*)d_ws;
  f16* embH   = (f16*)(ws + OFF_EMBH);
  f16* WiT    = (f16*)(ws + OFF_WIT);
  f16* Wfrag  = (f16*)(ws + OFF_WFRAG);
  float* bsum = (float*)(ws + OFF_BSUM);

  prep_emb_k<<<2560, 256, 0, stream>>>(emb, embH, V_ * DI_);
  prep_w_k<<<642, 256, 0, stream>>>(Wi, Wh, bi, bh, WiT, Wfrag, bsum);
  gemmA_k<<<dim3(4, 1024), 256, 0, stream>>>(X, embH, WiT, bsum, H);
  rnnB_k<<<8, 512, 0, stream>>>(h0, Wfrag, H);
}